// Round 18
// baseline (106.745 us; speedup 1.0000x reference)
//
#include <hip/hip_runtime.h>

#define LATENT 128
#define HIDDEN 256
#define OUTD   128
#define TT     100
#define DECH   64
#define NM     5    // RK4 macro-steps of 20 grid intervals (last = 19)

typedef _Float16 f16x8 __attribute__((ext_vector_type(8)));
typedef short    s16x8 __attribute__((ext_vector_type(8)));
typedef float    f32x4 __attribute__((ext_vector_type(4)));

#define MFMA16(a,b,c) __builtin_amdgcn_mfma_f32_16x16x32_f16((a),(b),(c),0,0,0)

__device__ __forceinline__ float tanh_fast(float x){
    float e = __expf(2.f*x);
    return 1.f - 2.f*__builtin_amdgcn_rcpf(e + 1.f);
}

// workgroup barrier WITHOUT vmcnt drain (cross-wave comms are LDS-only)
__device__ __forceinline__ void bar_nodrain(){
    __builtin_amdgcn_sched_barrier(0);
    asm volatile("s_waitcnt lgkmcnt(0)" ::: "memory");
    __builtin_amdgcn_sched_barrier(0);
    __builtin_amdgcn_s_barrier();
    __builtin_amdgcn_sched_barrier(0);
}

__device__ __forceinline__ f16x8 lds_rd8(const _Float16* b, int sB, int row, int colE){
    int off = row*sB + colE*2; off ^= (row&7)<<4;
    return *(const f16x8*)((const char*)b + off);
}
__device__ __forceinline__ void lds_wr1(_Float16* b, int sB, int row, int colE, float v){
    int off = row*sB + colE*2; off ^= (row&7)<<4;
    *(_Float16*)((char*)b + off) = (_Float16)v;
}
__device__ __forceinline__ void lds_wr2(_Float16* b, int sB, int row, int colE, float lo, float hi){
    int off = row*sB + colE*2; off ^= (row&7)<<4;
    union { _Float16 h[2]; unsigned u; } pk;
    pk.h[0] = (_Float16)lo; pk.h[1] = (_Float16)hi;
    *(unsigned*)((char*)b + off) = pk.u;
}
// relu on packed f16x8 via sign-mask (no NaN inputs here)
__device__ __forceinline__ f16x8 relu8(f16x8 v){
    s16x8 b = (s16x8)v;
    s16x8 m = b >> 15;
    b &= ~m;
    return (f16x8)b;
}

__device__ __forceinline__ f16x8 gbl_bfrag(const float* W, int ldN, int k0, int n){
    f16x8 f;
#pragma unroll
    for(int i=0;i<8;++i) f[i] = (_Float16)W[(size_t)(k0+i)*ldN + n];
    return f;
}
// B-frag in PACKED k-order: k_eff(i) = 32q + 4*lg + (i>>1) + 16*(i&1)
__device__ __forceinline__ f16x8 gbl_bfrag_pk(const float* W, int ldN, int q, int lg, int n){
    f16x8 f;
#pragma unroll
    for(int i=0;i<8;++i){
        int k = 32*q + 4*lg + (i>>1) + 16*(i&1);
        f[i] = (_Float16)W[(size_t)k*ldN + n];
    }
    return f;
}

__global__ __launch_bounds__(1024, 1) void ode_ws_kernel(
    const float* __restrict__ z0, const float* __restrict__ times,
    const float* __restrict__ W1, const float* __restrict__ b1,
    const float* __restrict__ W2, const float* __restrict__ b2,
    const float* __restrict__ dW1, const float* __restrict__ db1,
    const float* __restrict__ dW2, const float* __restrict__ db2,
    const float* __restrict__ dW3, const float* __restrict__ db3,
    float* __restrict__ out)
{
    __shared__ _Float16 z_lds[16*LATENT]   __attribute__((aligned(16))); // 4 KB  (chain)
    __shared__ _Float16 h_lds[16*HIDDEN]   __attribute__((aligned(16))); // 8 KB  (chain)
    __shared__ _Float16 epz[2][16*LATENT]  __attribute__((aligned(16))); // 8 KB  (handoff)
    __shared__ _Float16 epf[2][16*LATENT]  __attribute__((aligned(16))); // 8 KB
    __shared__ _Float16 uvT[16*DECH*2]     __attribute__((aligned(16))); // 4 KB  (UV transpose)
    __shared__ _Float16 h2p[2][64*DECH]    __attribute__((aligned(16))); // 16 KB (packed-k h2)
    __shared__ float    tl[TT];

    const int tid  = threadIdx.x;
    const int wv   = tid >> 6;       // 0..15
    const int lane = tid & 63;
    const int lr   = lane & 15;
    const int lg   = lane >> 4;
    const int row0 = 4*lg;
    const int gRow0 = blockIdx.x * 16;

    if(tid < TT) tl[tid] = times[tid];

    if(wv < 8){
        // ======================= CHAIN TEAM (waves 0-7) — R15 verbatim =======================
        const int wc = wv;
        f16x8 w1f[2][4];
#pragma unroll
        for(int t=0;t<2;++t)
#pragma unroll
            for(int q=0;q<4;++q)
                w1f[t][q] = gbl_bfrag(W1, HIDDEN, 32*q+8*lg, 32*wc+16*t+lr);
        f16x8 w2f[8];
#pragma unroll
        for(int q=0;q<8;++q)
            w2f[q] = gbl_bfrag_pk(W2, LATENT, q, lg, 16*wc+lr);
        const float b1v0 = b1[32*wc+lr], b1v1 = b1[32*wc+16+lr];
        const float b2v  = b2[16*wc+lr];

        f32x4 z, acc = {0,0,0,0};
#pragma unroll
        for(int r=0;r<4;++r){
            z[r] = z0[(size_t)(gRow0+row0+r)*LATENT + 16*wc + lr];
            lds_wr1(z_lds, LATENT*2, row0+r, 16*wc+lr, z[r]);
        }
        bar_nodrain();                                     // BAR init

        auto G1SEG = [&]{
            f16x8 az[4];
#pragma unroll
            for(int q=0;q<4;++q) az[q] = lds_rd8(z_lds, LATENT*2, lr, 32*q+8*lg);
            f32x4 c0 = {b1v0,b1v0,b1v0,b1v0};
            f32x4 c1 = {b1v1,b1v1,b1v1,b1v1};
#pragma unroll
            for(int q=0;q<4;++q){ c0 = MFMA16(az[q], w1f[0][q], c0); c1 = MFMA16(az[q], w1f[1][q], c1); }
#pragma unroll
            for(int r=0;r<4;++r)
                lds_wr2(h_lds, HIDDEN*2, row0+r, 2*(16*wc+lr), tanh_fast(c0[r]), tanh_fast(c1[r]));
        };
        auto G2SEG = [&]() -> f32x4 {
            f16x8 ah[8];
#pragma unroll
            for(int q=0;q<8;++q) ah[q] = lds_rd8(h_lds, HIDDEN*2, lr, 32*q+8*lg);
            f32x4 ca = {b2v,b2v,b2v,b2v}, cb = {0,0,0,0};
#pragma unroll
            for(int q=0;q<4;++q){ ca = MFMA16(ah[q], w2f[q], ca); cb = MFMA16(ah[4+q], w2f[4+q], cb); }
            return ca + cb;
        };
        auto WRZ = [&](f32x4 zs){
#pragma unroll
            for(int r=0;r<4;++r) lds_wr1(z_lds, LATENT*2, row0+r, 16*wc+lr, zs[r]);
        };
        auto WREP = [&](int par, f32x4 ff){
#pragma unroll
            for(int r=0;r<4;++r){
                lds_wr1(epz[par], LATENT*2, row0+r, 16*wc+lr, z[r]);
                lds_wr1(epf[par], LATENT*2, row0+r, 16*wc+lr, ff[r]);
            }
        };

#pragma unroll 1
        for(int j=0;j<NM;++j){
            const int  m0 = 20*j;
            const int  m1 = (m0+20 < TT-1) ? m0+20 : TT-1;
            const float hj = tl[m1]-tl[m0];

            G1SEG();  bar_nodrain();                       // s0a
            {
                f32x4 k1 = G2SEG();
                WREP(j&1, k1);
                acc = z + k1*(hj*(1.f/6.f));
                WRZ(z + k1*(hj*0.5f));
            }
            bar_nodrain();                                 // s0b
            G1SEG();  bar_nodrain();                       // s1a
            {
                f32x4 k2 = G2SEG();
                acc += k2*(hj*(1.f/3.f));
                WRZ(z + k2*(hj*0.5f));
            }
            bar_nodrain();                                 // s1b
            G1SEG();  bar_nodrain();                       // s2a
            {
                f32x4 k3 = G2SEG();
                acc += k3*(hj*(1.f/3.f));
                WRZ(z + k3*hj);
            }
            bar_nodrain();                                 // s2b
            G1SEG();  bar_nodrain();                       // s3a
            {
                f32x4 k4 = G2SEG();
                z = acc + k4*(hj*(1.f/6.f));
                WRZ(z);
            }
            bar_nodrain();                                 // s3b
        }
        // tail: T0 (G1), T1 (G2+WREP), then idle barriers T2..T7 (6)
        G1SEG();  bar_nodrain();                           // T0
        {
            f32x4 kt = G2SEG();
            WREP(NM&1, kt);
        }
        bar_nodrain();                                     // T1
        bar_nodrain(); bar_nodrain(); bar_nodrain();       // T2,T3,T4
        bar_nodrain(); bar_nodrain(); bar_nodrain();       // T5,T6,T7

    } else {
        // ======================= DECODE TEAM (waves 8-15) =======================
        const int dwv = wv - 8;        // 0..7
        const int mt  = dwv & 3;       // pt-tile for CMBDG2 / n-slice for UVG
        const int nh  = dwv >> 2;      // n2-half for CMBDG2; UVG write-gate
        // persistent decoder weights
        f16x8 dw2f[2][2], dw3f[2], db1f[2];
#pragma unroll
        for(int t=0;t<2;++t)
#pragma unroll
            for(int q=0;q<2;++q)
                dw2f[t][q] = gbl_bfrag(dW2, DECH, 32*q+8*lg, 32*nh+16*t+lr);
#pragma unroll
        for(int q=0;q<2;++q) dw3f[q] = gbl_bfrag_pk(dW3, OUTD, q, lg, 16*dwv+lr);
#pragma unroll
        for(int q=0;q<2;++q)
#pragma unroll
            for(int i=0;i<8;++i) db1f[q][i] = (_Float16)db1[32*q+8*lg+i];
        float db2v[2];
#pragma unroll
        for(int t=0;t<2;++t) db2v[t] = db2[32*nh+16*t+lr];
        const float db3v = db3[16*dwv+lr];

        f16x8 UAf[2], VAf[2], UBf[2], VBf[2];
#pragma unroll
        for(int q=0;q<2;++q){ UAf[q]=0; VAf[q]=0; UBf[q]=0; VBf[q]=0; }

        auto UVG = [&](int par){   // U,V = ep@dW1 (D-frags) -> uvT (UV-interleaved, packed b32)
            f32x4 u = {0,0,0,0}, v = {0,0,0,0};
#pragma unroll
            for(int q=0;q<4;++q){
                f16x8 w = gbl_bfrag(dW1, DECH, 32*q+8*lg, 16*mt+lr);  // reload per interval (reg relief)
                u = MFMA16(lds_rd8(epz[par], LATENT*2, lr, 32*q+8*lg), w, u);
                v = MFMA16(lds_rd8(epf[par], LATENT*2, lr, 32*q+8*lg), w, v);
            }
            if(nh==0){
#pragma unroll
                for(int rr=0;rr<4;++rr){
                    const int m = row0+rr, n1 = 16*mt+lr;
                    int off = m*256 + n1*4; off ^= (m&15)<<4;
                    union{ _Float16 h[2]; unsigned uu; } pk;
                    pk.h[0] = (_Float16)u[rr]; pk.h[1] = (_Float16)v[rr];
                    *(unsigned*)((char*)uvT + off) = pk.uu;
                }
            }
        };
        auto TRD = [&]{            // uvT -> UBf/VBf A-frags (rows=lr, k=n1)
#pragma unroll
            for(int q=0;q<2;++q)
#pragma unroll
                for(int h=0;h<2;++h){
                    int off = lr*256 + (32*q+8*lg)*4 + h*16; off ^= (lr&15)<<4;
                    f16x8 pr = *(const f16x8*)((const char*)uvT + off);
#pragma unroll
                    for(int e=0;e<4;++e){
                        UBf[q][4*h+e] = pr[2*e];
                        VBf[q][4*h+e] = pr[2*e+1];
                    }
                }
        };
        // fused Hermite-combine dG1 (registers) + dG2 -> h2p (packed cols)
        auto CMBDG2 = [&](int rid, float t0, float hp, float rhp){
            const int pt = 4*rid + mt;
            const float th = (tl[pt]-t0)*rhp, q2 = th*th, q3 = q2*th;
            const _Float16 a0h = (_Float16)(2.f*q3-3.f*q2+1.f);
            const _Float16 a1h = (_Float16)((q3-2.f*q2+th)*hp);
            const _Float16 a2h = (_Float16)(3.f*q2-2.f*q3);
            const _Float16 a3h = (_Float16)((q3-q2)*hp);
            f16x8 h1f[2];
#pragma unroll
            for(int q=0;q<2;++q){
                f16x8 v = UAf[q]*a0h + VAf[q]*a1h + UBf[q]*a2h + VBf[q]*a3h + db1f[q];
                h1f[q] = relu8(v);
            }
            f32x4 c0 = {db2v[0],db2v[0],db2v[0],db2v[0]};
            f32x4 c1 = {db2v[1],db2v[1],db2v[1],db2v[1]};
#pragma unroll
            for(int q=0;q<2;++q){ c0 = MFMA16(h1f[q], dw2f[0][q], c0); c1 = MFMA16(h1f[q], dw2f[1][q], c1); }
            _Float16* h2 = h2p[rid&1];
#pragma unroll
            for(int rr=0;rr<4;++rr){
                const int row = 16*mt + row0 + rr;
                int off = row*128 + 64*nh + 4*lr; off ^= (row&7)<<4;
                union{ _Float16 h[2]; unsigned uu; } pk;
                pk.h[0] = (_Float16)fmaxf(c0[rr],0.f);
                pk.h[1] = (_Float16)fmaxf(c1[rr],0.f);
                *(unsigned*)((char*)h2 + off) = pk.uu;
            }
        };
        auto DG3 = [&](int rid){   // h2p (packed k) @ dw3f_pk -> out
            const _Float16* h2 = h2p[rid&1];
            const int p0 = 4*rid;
#pragma unroll
            for(int mtp=0;mtp<4;++mtp){
                f32x4 cc = {db3v,db3v,db3v,db3v};
#pragma unroll
                for(int q=0;q<2;++q){
                    const int row = 16*mtp + lr;
                    int off = row*128 + (32*q+8*lg)*2; off ^= (row&7)<<4;
                    cc = MFMA16(*(const f16x8*)((const char*)h2 + off), dw3f[q], cc);
                }
#pragma unroll
                for(int rr=0;rr<4;++rr)
                    out[(size_t)(gRow0+row0+rr)*TT*OUTD + (size_t)(p0+mtp)*OUTD + 16*dwv+lr] = cc[rr];
            }
        };

        bar_nodrain();                                     // BAR init

#pragma unroll 1
        for(int j=0;j<NM;++j){
            const bool dA = (j>=1), dD = (j>=2);
            const int  rb = 5*(j-1);
            const float t0  = dA ? tl[20*(j-1)] : 1.f;
            const float hp  = dA ? (tl[20*j]-t0) : 1.f;
            const float rhp = 1.f/hp;

            // s0a: spillover last round of interval j-2
            if(dD) DG3(rb-1);
            bar_nodrain();
            // s0b: (chain publishes ep j)
            bar_nodrain();
            // s1a
            UVG(j&1);
            bar_nodrain();
            // s1b
            TRD();
            if(dA) CMBDG2(rb, t0, hp, rhp);
            bar_nodrain();
            // s2a
            if(dA){ CMBDG2(rb+1, t0, hp, rhp); DG3(rb); }
            bar_nodrain();
            // s2b
            if(dA){ CMBDG2(rb+2, t0, hp, rhp); DG3(rb+1); }
            bar_nodrain();
            // s3a
            if(dA){ CMBDG2(rb+3, t0, hp, rhp); DG3(rb+2); }
            bar_nodrain();
            // s3b
            if(dA){ CMBDG2(rb+4, t0, hp, rhp); DG3(rb+3); }
#pragma unroll
            for(int q=0;q<2;++q){ UAf[q]=UBf[q]; VAf[q]=VBf[q]; }
            bar_nodrain();
        }
        // tail: DG3(19); ep5 publish; decode interval 4 (rounds 20..24)
        {
            const float t0 = tl[80], hp = tl[TT-1]-t0, rhp = 1.f/hp;
            DG3(19);                                bar_nodrain();  // T0
                                                    bar_nodrain();  // T1 (chain publishes ep5)
            UVG(NM&1);                              bar_nodrain();  // T2
            TRD(); CMBDG2(20, t0, hp, rhp);         bar_nodrain();  // T3
            CMBDG2(21, t0, hp, rhp); DG3(20);       bar_nodrain();  // T4
            CMBDG2(22, t0, hp, rhp); DG3(21);       bar_nodrain();  // T5
            CMBDG2(23, t0, hp, rhp); DG3(22);       bar_nodrain();  // T6
            CMBDG2(24, t0, hp, rhp); DG3(23);       bar_nodrain();  // T7
            DG3(24);                                                // T8 (no barrier)
        }
    }
}

extern "C" void kernel_launch(void* const* d_in, const int* in_sizes, int n_in,
                              void* d_out, int out_size, void* d_ws, size_t ws_size,
                              hipStream_t stream) {
    ode_ws_kernel<<<dim3(256), dim3(1024), 0, stream>>>(
        (const float*)d_in[0],  (const float*)d_in[1],
        (const float*)d_in[2],  (const float*)d_in[3],
        (const float*)d_in[4],  (const float*)d_in[5],
        (const float*)d_in[6],  (const float*)d_in[7],
        (const float*)d_in[8],  (const float*)d_in[9],
        (const float*)d_in[10], (const float*)d_in[11],
        (float*)d_out);
}

// Round 19
// 63.418 us; speedup vs baseline: 1.6832x; 1.6832x over previous
//
#include <hip/hip_runtime.h>

#define LATENT 128
#define HIDDEN 256
#define OUTD   128
#define TT     100
#define DECH   64
#define NM     5    // RK4 macro-steps of 20 grid intervals (last = 19)

typedef _Float16 f16x8 __attribute__((ext_vector_type(8)));
typedef float    f32x4 __attribute__((ext_vector_type(4)));

#define MFMA16(a,b,c) __builtin_amdgcn_mfma_f32_16x16x32_f16((a),(b),(c),0,0,0)

__device__ __forceinline__ float tanh_fast(float x){
    float e = __expf(2.f*x);
    return 1.f - 2.f*__builtin_amdgcn_rcpf(e + 1.f);
}

// workgroup barrier WITHOUT vmcnt drain (cross-wave comms are LDS-only)
__device__ __forceinline__ void bar_nodrain(){
    __builtin_amdgcn_sched_barrier(0);
    asm volatile("s_waitcnt lgkmcnt(0)" ::: "memory");
    __builtin_amdgcn_sched_barrier(0);
    __builtin_amdgcn_s_barrier();
    __builtin_amdgcn_sched_barrier(0);
}

__device__ __forceinline__ f16x8 lds_rd8(const _Float16* b, int sB, int row, int colE){
    int off = row*sB + colE*2; off ^= (row&7)<<4;
    return *(const f16x8*)((const char*)b + off);
}
__device__ __forceinline__ void lds_wr1(_Float16* b, int sB, int row, int colE, float v){
    int off = row*sB + colE*2; off ^= (row&7)<<4;
    *(_Float16*)((char*)b + off) = (_Float16)v;
}
__device__ __forceinline__ void lds_wr2(_Float16* b, int sB, int row, int colE, float lo, float hi){
    int off = row*sB + colE*2; off ^= (row&7)<<4;
    union { _Float16 h[2]; unsigned u; } pk;
    pk.h[0] = (_Float16)lo; pk.h[1] = (_Float16)hi;
    *(unsigned*)((char*)b + off) = pk.u;
}

__device__ __forceinline__ f16x8 gbl_bfrag(const float* W, int ldN, int k0, int n){
    f16x8 f;
#pragma unroll
    for(int i=0;i<8;++i) f[i] = (_Float16)W[(size_t)(k0+i)*ldN + n];
    return f;
}
// B-frag in PACKED k-order: k_eff(i) = 32q + 4*lg + (i>>1) + 16*(i&1)
__device__ __forceinline__ f16x8 gbl_bfrag_pk(const float* W, int ldN, int q, int lg, int n){
    f16x8 f;
#pragma unroll
    for(int i=0;i<8;++i){
        int k = 32*q + 4*lg + (i>>1) + 16*(i&1);
        f[i] = (_Float16)W[(size_t)k*ldN + n];
    }
    return f;
}

__global__ __launch_bounds__(1024, 1) void ode_ws_kernel(
    const float* __restrict__ z0, const float* __restrict__ times,
    const float* __restrict__ W1, const float* __restrict__ b1,
    const float* __restrict__ W2, const float* __restrict__ b2,
    const float* __restrict__ dW1, const float* __restrict__ db1,
    const float* __restrict__ dW2, const float* __restrict__ db2,
    const float* __restrict__ dW3, const float* __restrict__ db3,
    float* __restrict__ out)
{
    __shared__ _Float16 z_lds[16*LATENT]   __attribute__((aligned(16))); // 4 KB  (chain)
    __shared__ _Float16 h_lds[16*HIDDEN]   __attribute__((aligned(16))); // 8 KB  (chain)
    __shared__ _Float16 epz[2][16*LATENT]  __attribute__((aligned(16))); // 8 KB  (handoff)
    __shared__ _Float16 epf[2][16*LATENT]  __attribute__((aligned(16))); // 8 KB
    __shared__ _Float16 h1i[2][64*DECH]    __attribute__((aligned(16))); // 16 KB (decode)
    __shared__ _Float16 h2p[2][64*DECH]    __attribute__((aligned(16))); // 16 KB (packed-col h2)
    __shared__ float    tl[TT];

    const int tid  = threadIdx.x;
    const int wv   = tid >> 6;       // 0..15
    const int lane = tid & 63;
    const int lr   = lane & 15;
    const int lg   = lane >> 4;
    const int row0 = 4*lg;
    const int gRow0 = blockIdx.x * 16;

    if(tid < TT) tl[tid] = times[tid];

    if(wv < 8){
        // ======================= CHAIN TEAM (waves 0-7) — R15 verbatim =======================
        const int wc = wv;
        f16x8 w1f[2][4];
#pragma unroll
        for(int t=0;t<2;++t)
#pragma unroll
            for(int q=0;q<4;++q)
                w1f[t][q] = gbl_bfrag(W1, HIDDEN, 32*q+8*lg, 32*wc+16*t+lr);
        f16x8 w2f[8];
#pragma unroll
        for(int q=0;q<8;++q)
            w2f[q] = gbl_bfrag_pk(W2, LATENT, q, lg, 16*wc+lr);
        const float b1v0 = b1[32*wc+lr], b1v1 = b1[32*wc+16+lr];
        const float b2v  = b2[16*wc+lr];

        f32x4 z, acc = {0,0,0,0};
#pragma unroll
        for(int r=0;r<4;++r){
            z[r] = z0[(size_t)(gRow0+row0+r)*LATENT + 16*wc + lr];
            lds_wr1(z_lds, LATENT*2, row0+r, 16*wc+lr, z[r]);
        }
        bar_nodrain();                                     // BAR init

        auto G1SEG = [&]{
            f16x8 az[4];
#pragma unroll
            for(int q=0;q<4;++q) az[q] = lds_rd8(z_lds, LATENT*2, lr, 32*q+8*lg);
            f32x4 c0 = {b1v0,b1v0,b1v0,b1v0};
            f32x4 c1 = {b1v1,b1v1,b1v1,b1v1};
#pragma unroll
            for(int q=0;q<4;++q){ c0 = MFMA16(az[q], w1f[0][q], c0); c1 = MFMA16(az[q], w1f[1][q], c1); }
#pragma unroll
            for(int r=0;r<4;++r)
                lds_wr2(h_lds, HIDDEN*2, row0+r, 2*(16*wc+lr), tanh_fast(c0[r]), tanh_fast(c1[r]));
        };
        auto G2SEG = [&]() -> f32x4 {
            f16x8 ah[8];
#pragma unroll
            for(int q=0;q<8;++q) ah[q] = lds_rd8(h_lds, HIDDEN*2, lr, 32*q+8*lg);
            f32x4 ca = {b2v,b2v,b2v,b2v}, cb = {0,0,0,0};
#pragma unroll
            for(int q=0;q<4;++q){ ca = MFMA16(ah[q], w2f[q], ca); cb = MFMA16(ah[4+q], w2f[4+q], cb); }
            return ca + cb;
        };
        auto WRZ = [&](f32x4 zs){
#pragma unroll
            for(int r=0;r<4;++r) lds_wr1(z_lds, LATENT*2, row0+r, 16*wc+lr, zs[r]);
        };
        auto WREP = [&](int par, f32x4 ff){
#pragma unroll
            for(int r=0;r<4;++r){
                lds_wr1(epz[par], LATENT*2, row0+r, 16*wc+lr, z[r]);
                lds_wr1(epf[par], LATENT*2, row0+r, 16*wc+lr, ff[r]);
            }
        };

#pragma unroll 1
        for(int j=0;j<NM;++j){
            const int  m0 = 20*j;
            const int  m1 = (m0+20 < TT-1) ? m0+20 : TT-1;
            const float hj = tl[m1]-tl[m0];

            G1SEG();  bar_nodrain();                       // s0a
            {
                f32x4 k1 = G2SEG();
                WREP(j&1, k1);
                acc = z + k1*(hj*(1.f/6.f));
                WRZ(z + k1*(hj*0.5f));
            }
            bar_nodrain();                                 // s0b
            G1SEG();  bar_nodrain();                       // s1a
            {
                f32x4 k2 = G2SEG();
                acc += k2*(hj*(1.f/3.f));
                WRZ(z + k2*(hj*0.5f));
            }
            bar_nodrain();                                 // s1b
            G1SEG();  bar_nodrain();                       // s2a
            {
                f32x4 k3 = G2SEG();
                acc += k3*(hj*(1.f/3.f));
                WRZ(z + k3*hj);
            }
            bar_nodrain();                                 // s2b
            G1SEG();  bar_nodrain();                       // s3a
            {
                f32x4 k4 = G2SEG();
                z = acc + k4*(hj*(1.f/6.f));
                WRZ(z);
            }
            bar_nodrain();                                 // s3b
        }
        // tail: T0 (G1), T1 (G2+WREP), then idle barriers T2..T9; T10 no barrier
        G1SEG();  bar_nodrain();                           // T0
        {
            f32x4 kt = G2SEG();
            WREP(NM&1, kt);
        }
        bar_nodrain();                                     // T1
        bar_nodrain(); bar_nodrain(); bar_nodrain();       // T2,T3,T4
        bar_nodrain(); bar_nodrain(); bar_nodrain();       // T5,T6,T7
        bar_nodrain(); bar_nodrain();                      // T8,T9

    } else {
        // ======================= DECODE TEAM (waves 8-15) =======================
        const int dwv = wv - 8;        // 0..7
        const int nsl = dwv & 3;       // CMB: n-slice (16 cols)
        const int ph  = dwv >> 2;      // CMB: point-half
        const int mt2 = dwv & 3;       // DG2: pt-tile
        const int nh  = dwv >> 2;      // DG2: packed col-half (2x16)
        const int mh  = dwv >> 2;      // DG3: m-half
        const int ncl = dwv & 3;       // DG3: 32-col n-group
        f16x8 dw1f[4], dw2f[2][2], dw3f[2][2];
#pragma unroll
        for(int q=0;q<4;++q) dw1f[q] = gbl_bfrag(dW1, DECH, 32*q+8*lg, 16*nsl+lr);
#pragma unroll
        for(int t=0;t<2;++t)
#pragma unroll
            for(int q=0;q<2;++q)
                dw2f[t][q] = gbl_bfrag(dW2, DECH, 32*q+8*lg, 32*nh+16*t+lr);
#pragma unroll
        for(int nt=0;nt<2;++nt)
#pragma unroll
            for(int q=0;q<2;++q)
                dw3f[nt][q] = gbl_bfrag_pk(dW3, OUTD, q, lg, 16*(2*ncl+nt)+lr);
        const float db1v = db1[16*nsl+lr];
        float db2v[2], db3v[2];
#pragma unroll
        for(int t=0;t<2;++t) db2v[t] = db2[32*nh+16*t+lr];
#pragma unroll
        for(int nt=0;nt<2;++nt) db3v[nt] = db3[16*(2*ncl+nt)+lr];

        f32x4 UA={0,0,0,0}, VA={0,0,0,0}, UB={0,0,0,0}, VB={0,0,0,0};

        auto UVGEMM = [&](int par){
            f32x4 u = {0,0,0,0}, v = {0,0,0,0};
#pragma unroll
            for(int q=0;q<4;++q){
                u = MFMA16(lds_rd8(epz[par], LATENT*2, lr, 32*q+8*lg), dw1f[q], u);
                v = MFMA16(lds_rd8(epf[par], LATENT*2, lr, 32*q+8*lg), dw1f[q], v);
            }
            UB = u; VB = v;
        };
        auto CMB = [&](int rid, float t0, float hp, float rhp){
            _Float16* h1 = h1i[rid&1];
            const int p0 = 4*rid;
#pragma unroll
            for(int i=0;i<2;++i){
                const int pi = 2*ph + i;
                const float th = (tl[p0+pi]-t0)*rhp;
                const float t2 = th*th, t3 = t2*th;
                const float a0 = 2.f*t3-3.f*t2+1.f, a1 = (t3-2.f*t2+th)*hp;
                const float a2 = 3.f*t2-2.f*t3,     a3 = (t3-t2)*hp;
#pragma unroll
                for(int rr=0;rr<4;++rr){
                    float v = a0*UA[rr] + a1*VA[rr] + a2*UB[rr] + a3*VB[rr] + db1v;
                    lds_wr1(h1, DECH*2, 16*pi+row0+rr, 16*nsl+lr, fmaxf(v,0.f));
                }
            }
        };
        auto DG2 = [&](int rid){   // packed-h2: one pt-tile, 2x16 cols -> b32 pair writes
            const _Float16* h1 = h1i[rid&1];
            _Float16* h2 = h2p[rid&1];
            f32x4 c0 = {db2v[0],db2v[0],db2v[0],db2v[0]};
            f32x4 c1 = {db2v[1],db2v[1],db2v[1],db2v[1]};
#pragma unroll
            for(int q=0;q<2;++q){
                f16x8 a = lds_rd8(h1, DECH*2, 16*mt2+lr, 32*q+8*lg);
                c0 = MFMA16(a, dw2f[0][q], c0);
                c1 = MFMA16(a, dw2f[1][q], c1);
            }
#pragma unroll
            for(int rr=0;rr<4;++rr){
                const int row = 16*mt2 + row0 + rr;
                int off = row*128 + 64*nh + 4*lr; off ^= (row&7)<<4;
                union{ _Float16 h[2]; unsigned uu; } pk;
                pk.h[0] = (_Float16)fmaxf(c0[rr],0.f);
                pk.h[1] = (_Float16)fmaxf(c1[rr],0.f);
                *(unsigned*)((char*)h2 + off) = pk.uu;
            }
        };
        auto DG3 = [&](int rid){   // m-split + packed-k A-reads
            const _Float16* h2 = h2p[rid&1];
            const int p0 = 4*rid;
#pragma unroll
            for(int m=0;m<2;++m){
                const int mt = 2*mh + m;
                f16x8 a[2];
#pragma unroll
                for(int q=0;q<2;++q){
                    const int row = 16*mt + lr;
                    int off = row*128 + (32*q+8*lg)*2; off ^= (row&7)<<4;
                    a[q] = *(const f16x8*)((const char*)h2 + off);
                }
#pragma unroll
                for(int nt=0;nt<2;++nt){
                    f32x4 cc = {db3v[nt],db3v[nt],db3v[nt],db3v[nt]};
#pragma unroll
                    for(int q=0;q<2;++q) cc = MFMA16(a[q], dw3f[nt][q], cc);
#pragma unroll
                    for(int rr=0;rr<4;++rr)
                        out[(size_t)(gRow0+row0+rr)*TT*OUTD + (size_t)(p0+mt)*OUTD + 16*(2*ncl+nt)+lr] = cc[rr];
                }
            }
        };

        bar_nodrain();                                     // BAR init

#pragma unroll 1
        for(int j=0;j<NM;++j){
            const bool dA = (j>=1);
            const bool dD = (j>=2);
            const int  rb = 5*(j-1);           // rounds of interval j-1
            const int  rs = 5*(j-2);           // spillover rounds of interval j-2
            const float t0  = dA ? tl[20*(j-1)] : 1.f;
            const float hp  = dA ? (tl[20*j]-t0) : 1.f;
            const float rhp = 1.f/hp;

            // s0a
            if(dD){ DG2(rs+4); DG3(rs+3); }
            bar_nodrain();
            // s0b
            if(dD) DG3(rs+4);
            bar_nodrain();
            // s1a
            UVGEMM(j&1);
            bar_nodrain();
            // s1b
            if(dA) CMB(rb, t0, hp, rhp);
            bar_nodrain();
            // s2a
            if(dA){ CMB(rb+1, t0, hp, rhp); DG2(rb); }
            bar_nodrain();
            // s2b
            if(dA){ CMB(rb+2, t0, hp, rhp); DG2(rb+1); DG3(rb); }
            bar_nodrain();
            // s3a
            if(dA){ CMB(rb+3, t0, hp, rhp); DG2(rb+2); DG3(rb+1); }
            bar_nodrain();
            // s3b
            if(dA){ CMB(rb+4, t0, hp, rhp); DG2(rb+3); DG3(rb+2); }
            UA = UB; VA = VB;
            bar_nodrain();
        }
        // tail: finish interval 3 (rounds 18,19) + decode interval 4 (rounds 20..24)
        {
            const float t0 = tl[80], hp = tl[TT-1]-t0, rhp = 1.f/hp;
            DG2(19); DG3(18);                       bar_nodrain();  // T0
            DG3(19);                                bar_nodrain();  // T1
            UVGEMM(NM&1);                           bar_nodrain();  // T2
            CMB(20, t0, hp, rhp);                   bar_nodrain();  // T3
            CMB(21, t0, hp, rhp); DG2(20);          bar_nodrain();  // T4
            CMB(22, t0, hp, rhp); DG2(21); DG3(20); bar_nodrain();  // T5
            CMB(23, t0, hp, rhp); DG2(22); DG3(21); bar_nodrain();  // T6
            CMB(24, t0, hp, rhp); DG2(23); DG3(22); bar_nodrain();  // T7
            DG2(24); DG3(23);                       bar_nodrain();  // T8
            DG3(24);                                bar_nodrain();  // T9
            // (no more work; T10 none)
        }
    }
}

extern "C" void kernel_launch(void* const* d_in, const int* in_sizes, int n_in,
                              void* d_out, int out_size, void* d_ws, size_t ws_size,
                              hipStream_t stream) {
    ode_ws_kernel<<<dim3(256), dim3(1024), 0, stream>>>(
        (const float*)d_in[0],  (const float*)d_in[1],
        (const float*)d_in[2],  (const float*)d_in[3],
        (const float*)d_in[4],  (const float*)d_in[5],
        (const float*)d_in[6],  (const float*)d_in[7],
        (const float*)d_in[8],  (const float*)d_in[9],
        (const float*)d_in[10], (const float*)d_in[11],
        (float*)d_out);
}

// Round 20
// 57.842 us; speedup vs baseline: 1.8455x; 1.0964x over previous
//
#include <hip/hip_runtime.h>

#define LATENT 128
#define HIDDEN 256
#define OUTD   128
#define TT     100
#define DECH   64
#define NM     5    // RK4 macro-steps of 20 grid intervals (last = 19)

typedef _Float16 f16x8 __attribute__((ext_vector_type(8)));
typedef float    f32x4 __attribute__((ext_vector_type(4)));

#define MFMA16(a,b,c) __builtin_amdgcn_mfma_f32_16x16x32_f16((a),(b),(c),0,0,0)

__device__ __forceinline__ float tanh_fast(float x){
    float e = __expf(2.f*x);
    return 1.f - 2.f*__builtin_amdgcn_rcpf(e + 1.f);
}

// workgroup barrier WITHOUT vmcnt drain (cross-wave comms are LDS-only)
__device__ __forceinline__ void bar_nodrain(){
    __builtin_amdgcn_sched_barrier(0);
    asm volatile("s_waitcnt lgkmcnt(0)" ::: "memory");
    __builtin_amdgcn_sched_barrier(0);
    __builtin_amdgcn_s_barrier();
    __builtin_amdgcn_sched_barrier(0);
}

__device__ __forceinline__ f16x8 lds_rd8(const _Float16* b, int sB, int row, int colE){
    int off = row*sB + colE*2; off ^= (row&7)<<4;
    return *(const f16x8*)((const char*)b + off);
}
__device__ __forceinline__ void lds_wr1(_Float16* b, int sB, int row, int colE, float v){
    int off = row*sB + colE*2; off ^= (row&7)<<4;
    *(_Float16*)((char*)b + off) = (_Float16)v;
}
__device__ __forceinline__ void lds_wr2(_Float16* b, int sB, int row, int colE, float lo, float hi){
    int off = row*sB + colE*2; off ^= (row&7)<<4;
    union { _Float16 h[2]; unsigned u; } pk;
    pk.h[0] = (_Float16)lo; pk.h[1] = (_Float16)hi;
    *(unsigned*)((char*)b + off) = pk.u;
}

__device__ __forceinline__ f16x8 gbl_bfrag(const float* W, int ldN, int k0, int n){
    f16x8 f;
#pragma unroll
    for(int i=0;i<8;++i) f[i] = (_Float16)W[(size_t)(k0+i)*ldN + n];
    return f;
}
__device__ __forceinline__ f16x8 gbl_bfrag_pk(const float* W, int ldN, int q, int lg, int n){
    f16x8 f;
#pragma unroll
    for(int i=0;i<8;++i){
        int k = 32*q + 4*lg + (i>>1) + 16*(i&1);
        f[i] = (_Float16)W[(size_t)k*ldN + n];
    }
    return f;
}

__global__ __launch_bounds__(1024, 1) void ode_ws_kernel(
    const float* __restrict__ z0, const float* __restrict__ times,
    const float* __restrict__ W1, const float* __restrict__ b1,
    const float* __restrict__ W2, const float* __restrict__ b2,
    const float* __restrict__ dW1, const float* __restrict__ db1,
    const float* __restrict__ dW2, const float* __restrict__ db2,
    const float* __restrict__ dW3, const float* __restrict__ db3,
    float* __restrict__ out)
{
    __shared__ _Float16 z_lds[16*LATENT]   __attribute__((aligned(16))); // 4 KB  (chain)
    __shared__ _Float16 h_lds[16*HIDDEN]   __attribute__((aligned(16))); // 8 KB  (chain)
    __shared__ _Float16 epz[2][16*LATENT]  __attribute__((aligned(16))); // 8 KB  (handoff)
    __shared__ _Float16 epf[2][16*LATENT]  __attribute__((aligned(16))); // 8 KB
    __shared__ _Float16 h1i[2][64*DECH]    __attribute__((aligned(16))); // 16 KB (decode)
    __shared__ _Float16 h2i[2][64*DECH]    __attribute__((aligned(16))); // 16 KB
    __shared__ float    tl[TT];

    const int tid  = threadIdx.x;
    const int wv   = tid >> 6;       // 0..15
    const int lane = tid & 63;
    const int lr   = lane & 15;
    const int lg   = lane >> 4;
    const int row0 = 4*lg;
    const int gRow0 = blockIdx.x * 16;

    if(tid < TT) tl[tid] = times[tid];

    if(wv < 8){
        // ======================= CHAIN TEAM (waves 0-7) =======================
        const int wc = wv;
        f16x8 w1f[2][4];
#pragma unroll
        for(int t=0;t<2;++t)
#pragma unroll
            for(int q=0;q<4;++q)
                w1f[t][q] = gbl_bfrag(W1, HIDDEN, 32*q+8*lg, 32*wc+16*t+lr);
        f16x8 w2f[8];
#pragma unroll
        for(int q=0;q<8;++q)
            w2f[q] = gbl_bfrag_pk(W2, LATENT, q, lg, 16*wc+lr);
        const float b1v0 = b1[32*wc+lr], b1v1 = b1[32*wc+16+lr];
        const float b2v  = b2[16*wc+lr];

        f32x4 z, acc = {0,0,0,0};
#pragma unroll
        for(int r=0;r<4;++r){
            z[r] = z0[(size_t)(gRow0+row0+r)*LATENT + 16*wc + lr];
            lds_wr1(z_lds, LATENT*2, row0+r, 16*wc+lr, z[r]);
        }
        bar_nodrain();                                     // BAR init

        auto G1SEG = [&]{
            f16x8 az[4];
#pragma unroll
            for(int q=0;q<4;++q) az[q] = lds_rd8(z_lds, LATENT*2, lr, 32*q+8*lg);
            f32x4 c0 = {b1v0,b1v0,b1v0,b1v0};
            f32x4 c1 = {b1v1,b1v1,b1v1,b1v1};
#pragma unroll
            for(int q=0;q<4;++q){ c0 = MFMA16(az[q], w1f[0][q], c0); c1 = MFMA16(az[q], w1f[1][q], c1); }
#pragma unroll
            for(int r=0;r<4;++r)
                lds_wr2(h_lds, HIDDEN*2, row0+r, 2*(16*wc+lr), tanh_fast(c0[r]), tanh_fast(c1[r]));
        };
        auto G2SEG = [&]() -> f32x4 {
            f16x8 ah[8];
#pragma unroll
            for(int q=0;q<8;++q) ah[q] = lds_rd8(h_lds, HIDDEN*2, lr, 32*q+8*lg);
            f32x4 ca = {b2v,b2v,b2v,b2v}, cb = {0,0,0,0};
#pragma unroll
            for(int q=0;q<4;++q){ ca = MFMA16(ah[q], w2f[q], ca); cb = MFMA16(ah[4+q], w2f[4+q], cb); }
            return ca + cb;
        };
        auto WRZ = [&](f32x4 zs){
#pragma unroll
            for(int r=0;r<4;++r) lds_wr1(z_lds, LATENT*2, row0+r, 16*wc+lr, zs[r]);
        };
        auto WREP = [&](int par, f32x4 ff){
#pragma unroll
            for(int r=0;r<4;++r){
                lds_wr1(epz[par], LATENT*2, row0+r, 16*wc+lr, z[r]);
                lds_wr1(epf[par], LATENT*2, row0+r, 16*wc+lr, ff[r]);
            }
        };

#pragma unroll 1
        for(int j=0;j<NM;++j){
            const int  m0 = 20*j;
            const int  m1 = (m0+20 < TT-1) ? m0+20 : TT-1;
            const float hj = tl[m1]-tl[m0];

            G1SEG();  bar_nodrain();                       // s0a
            {
                f32x4 k1 = G2SEG();
                WREP(j&1, k1);
                acc = z + k1*(hj*(1.f/6.f));
                WRZ(z + k1*(hj*0.5f));
            }
            bar_nodrain();                                 // s0b
            G1SEG();  bar_nodrain();                       // s1a
            {
                f32x4 k2 = G2SEG();
                acc += k2*(hj*(1.f/3.f));
                WRZ(z + k2*(hj*0.5f));
            }
            bar_nodrain();                                 // s1b
            G1SEG();  bar_nodrain();                       // s2a
            {
                f32x4 k3 = G2SEG();
                acc += k3*(hj*(1.f/3.f));
                WRZ(z + k3*hj);
            }
            bar_nodrain();                                 // s2b
            G1SEG();  bar_nodrain();                       // s3a
            {
                f32x4 k4 = G2SEG();
                z = acc + k4*(hj*(1.f/6.f));
                WRZ(z);
            }
            bar_nodrain();                                 // s3b
        }
        // tail: T0 (G1), T1 (G2+WREP), then idle barriers T2..T9; T10 no barrier
        G1SEG();  bar_nodrain();                           // T0
        {
            f32x4 kt = G2SEG();
            WREP(NM&1, kt);
        }
        bar_nodrain();                                     // T1
        bar_nodrain(); bar_nodrain(); bar_nodrain();       // T2,T3,T4
        bar_nodrain(); bar_nodrain(); bar_nodrain();       // T5,T6,T7
        bar_nodrain(); bar_nodrain();                      // T8,T9

    } else {
        // ======================= DECODE TEAM (waves 8-15) =======================
        const int dwv = wv - 8;        // 0..7
        const int nsl = dwv & 3;       // n-slice (16 cols) for CMB/DG2
        const int ph  = dwv >> 2;      // point-half (CMB) / m-half (DG2)
        f16x8 dw1f[4], dw2f[2], dw3f[2];
#pragma unroll
        for(int q=0;q<4;++q) dw1f[q] = gbl_bfrag(dW1, DECH, 32*q+8*lg, 16*nsl+lr);
#pragma unroll
        for(int q=0;q<2;++q) dw2f[q] = gbl_bfrag(dW2, DECH, 32*q+8*lg, 16*nsl+lr);
#pragma unroll
        for(int q=0;q<2;++q) dw3f[q] = gbl_bfrag(dW3, OUTD, 32*q+8*lg, 16*dwv+lr);
        const float db1v = db1[16*nsl+lr], db2v = db2[16*nsl+lr];
        const float db3v = db3[16*dwv+lr];

        f32x4 UA={0,0,0,0}, VA={0,0,0,0}, UB={0,0,0,0}, VB={0,0,0,0};

        auto UVGEMM = [&](int par){
            f32x4 u = {0,0,0,0}, v = {0,0,0,0};
#pragma unroll
            for(int q=0;q<4;++q){
                u = MFMA16(lds_rd8(epz[par], LATENT*2, lr, 32*q+8*lg), dw1f[q], u);
                v = MFMA16(lds_rd8(epf[par], LATENT*2, lr, 32*q+8*lg), dw1f[q], v);
            }
            UB = u; VB = v;
        };
        auto CMB = [&](int rid, int p0, float t0, float hp, float rhp){
            _Float16* h1 = h1i[rid&1];
#pragma unroll
            for(int i=0;i<2;++i){
                const int pi = 2*ph + i;
                const float th = (tl[p0+pi]-t0)*rhp;
                const float t2 = th*th, t3 = t2*th;
                const float a0 = 2.f*t3-3.f*t2+1.f, a1 = (t3-2.f*t2+th)*hp;
                const float a2 = 3.f*t2-2.f*t3,     a3 = (t3-t2)*hp;
#pragma unroll
                for(int rr=0;rr<4;++rr){
                    float v = a0*UA[rr] + a1*VA[rr] + a2*UB[rr] + a3*VB[rr] + db1v;
                    lds_wr1(h1, DECH*2, 16*pi+row0+rr, 16*nsl+lr, fmaxf(v,0.f));
                }
            }
        };
        auto DG2 = [&](int rid){
            const _Float16* h1 = h1i[rid&1];
            _Float16* h2 = h2i[rid&1];
#pragma unroll
            for(int c=0;c<2;++c){ const int mt = 2*ph+c;
                f32x4 cc = {db2v,db2v,db2v,db2v};
#pragma unroll
                for(int q=0;q<2;++q) cc = MFMA16(lds_rd8(h1, DECH*2, 16*mt+lr, 32*q+8*lg), dw2f[q], cc);
#pragma unroll
                for(int rr=0;rr<4;++rr) lds_wr1(h2, DECH*2, 16*mt+row0+rr, 16*nsl+lr, fmaxf(cc[rr],0.f));
            }
        };
        auto DG3 = [&](int rid, int p0){
            const _Float16* h2 = h2i[rid&1];
#pragma unroll
            for(int mt=0;mt<4;++mt){
                f32x4 cc = {db3v,db3v,db3v,db3v};
#pragma unroll
                for(int q=0;q<2;++q) cc = MFMA16(lds_rd8(h2, DECH*2, 16*mt+lr, 32*q+8*lg), dw3f[q], cc);
#pragma unroll
                for(int rr=0;rr<4;++rr)
                    out[(size_t)(gRow0+row0+rr)*TT*OUTD + (size_t)(p0+mt)*OUTD + 16*dwv+lr] = cc[rr];
            }
        };

        bar_nodrain();                                     // BAR init

#pragma unroll 1
        for(int j=0;j<NM;++j){
            const bool dA = (j>=1);
            const bool dD = (j>=2);
            const int  rb = 5*(j-1);           // first rid of interval j-1
            const int  rs = 5*(j-2);           // first rid of interval j-2 (spillover)
            const int  pb = 20*(j-1);          // first pt of interval j-1
            const float t0  = dA ? tl[20*(j-1)] : 1.f;
            const float hp  = dA ? (tl[20*j]-t0) : 1.f;
            const float rhp = 1.f/hp;

            // s0a
            if(dD){ DG2(rs+4); DG3(rs+3, 20*(j-2)+12); }
            bar_nodrain();
            // s0b
            if(dD){ DG3(rs+4, 20*(j-2)+16); }
            bar_nodrain();
            // s1a
            UVGEMM(j&1);
            bar_nodrain();
            // s1b
            if(dA) CMB(rb, pb, t0, hp, rhp);
            bar_nodrain();
            // s2a
            if(dA){ CMB(rb+1, pb+4, t0, hp, rhp); DG2(rb); }
            bar_nodrain();
            // s2b
            if(dA){ CMB(rb+2, pb+8, t0, hp, rhp); DG2(rb+1); DG3(rb, pb); }
            bar_nodrain();
            // s3a
            if(dA){ CMB(rb+3, pb+12, t0, hp, rhp); DG2(rb+2); DG3(rb+1, pb+4); }
            bar_nodrain();
            // s3b
            if(dA){ CMB(rb+4, pb+16, t0, hp, rhp); DG2(rb+3); DG3(rb+2, pb+8); }
            UA = UB; VA = VB;
            bar_nodrain();
        }
        // tail: interval 3 spillover + interval 4 (rids 20..24, pts 80..99)
        {
            const float t0 = tl[80], hp = tl[TT-1]-t0, rhp = 1.f/hp;
            DG2(19); DG3(18, 72);            bar_nodrain();  // T0
            DG3(19, 76);                     bar_nodrain();  // T1
            UVGEMM(NM&1);                    bar_nodrain();  // T2
            CMB(20, 80, t0, hp, rhp);        bar_nodrain();  // T3
            CMB(21, 84, t0, hp, rhp); DG2(20);               bar_nodrain();  // T4
            CMB(22, 88, t0, hp, rhp); DG2(21); DG3(20, 80);  bar_nodrain();  // T5
            CMB(23, 92, t0, hp, rhp); DG2(22); DG3(21, 84);  bar_nodrain();  // T6
            CMB(24, 96, t0, hp, rhp); DG2(23); DG3(22, 88);  bar_nodrain();  // T7
            DG2(24); DG3(23, 92);            bar_nodrain();  // T8
            DG3(24, 96);                                     // T9 (no barrier)
        }
    }
}

extern "C" void kernel_launch(void* const* d_in, const int* in_sizes, int n_in,
                              void* d_out, int out_size, void* d_ws, size_t ws_size,
                              hipStream_t stream) {
    ode_ws_kernel<<<dim3(256), dim3(1024), 0, stream>>>(
        (const float*)d_in[0],  (const float*)d_in[1],
        (const float*)d_in[2],  (const float*)d_in[3],
        (const float*)d_in[4],  (const float*)d_in[5],
        (const float*)d_in[6],  (const float*)d_in[7],
        (const float*)d_in[8],  (const float*)d_in[9],
        (const float*)d_in[10], (const float*)d_in[11],
        (float*)d_out);
}